// Round 3
// baseline (370.300 us; speedup 1.0000x reference)
//
#include <hip/hip_runtime.h>
#include <math.h>
#include <stdint.h>

#define B_ 4
#define T_ 2048
#define C_ 1024
#define H_ 16
#define G_ 4
#define D_ 64
#define KVC_ 512   // 2*G*D

typedef unsigned short u16;
typedef short bf16x8 __attribute__((ext_vector_type(8)));
typedef float f32x4 __attribute__((ext_vector_type(4)));

__device__ __forceinline__ u16 f2bf(float f) {
  uint32_t u = __builtin_bit_cast(uint32_t, f);
  u += 0x7fffu + ((u >> 16) & 1u);   // RNE
  return (u16)(u >> 16);
}

__device__ __forceinline__ void gload16(const void* g, void* l) {
  __builtin_amdgcn_global_load_lds((const __attribute__((address_space(1))) void*)g,
                                   (__attribute__((address_space(3))) void*)l, 16, 0, 0);
}

// ---------------------------------------------------------------------------
// fp32 -> bf16 (scale folded in), vectorized x4
// ---------------------------------------------------------------------------
__global__ __launch_bounds__(256)
void cvt_bf16(const float* __restrict__ s, u16* __restrict__ d, int n4, float scale) {
  int i = blockIdx.x * 256 + threadIdx.x;
  const int stride = gridDim.x * 256;
  for (; i < n4; i += stride) {
    const float4 v = ((const float4*)s)[i];
    uint2 o;
    o.x = (uint32_t)f2bf(v.x * scale) | ((uint32_t)f2bf(v.y * scale) << 16);
    o.y = (uint32_t)f2bf(v.z * scale) | ((uint32_t)f2bf(v.w * scale) << 16);
    ((uint2*)d)[i] = o;
  }
}

// ---------------------------------------------------------------------------
// bf16 GEMM, m97 structure: out[M,N] = A[M,K] @ W[N,K]^T
// 128x128 tile, BK=32, 256 thr / 4 waves (2x2), 4x4 16x16x32 frags per wave.
// OUTF32=0: bf16 out.  OUTF32=1: f32 out + bias.
// ---------------------------------------------------------------------------
template <int OUTF32>
__global__ __launch_bounds__(256)
void gemm_bf16(const u16* __restrict__ A, const u16* __restrict__ W,
               const float* __restrict__ bias, void* __restrict__ outp,
               int N, int K) {
  __shared__ __align__(16) u16 As[128 * 32];
  __shared__ __align__(16) u16 Ws[128 * 32];
  const int tid = threadIdx.x;
  const int l = tid & 63, w = tid >> 6;
  const int lhi = l >> 4, llo = l & 15;
  const int wr = w >> 1, wc = w & 1;
  const int m0 = blockIdx.x * 128, n0 = blockIdx.y * 128;

  const u16* a_src = A + (size_t)(m0 + 32 * w + (l >> 2)) * K + 8 * (l & 3);
  const u16* w_src = W + (size_t)(n0 + 32 * w + (l >> 2)) * K + 8 * (l & 3);
  u16* asl = As + 1024 * w;   // wave-uniform LDS dests
  u16* wsl = Ws + 1024 * w;

  const f32x4 zero4 = {0.f, 0.f, 0.f, 0.f};
  f32x4 acc[4][4];
#pragma unroll
  for (int i = 0; i < 4; ++i)
#pragma unroll
    for (int j = 0; j < 4; ++j) acc[i][j] = zero4;

  for (int k0 = 0; k0 < K; k0 += 32) {
    __syncthreads();
    gload16(a_src + k0, asl);
    gload16(a_src + k0 + 16 * K, asl + 512);
    gload16(w_src + k0, wsl);
    gload16(w_src + k0 + 16 * K, wsl + 512);
    __syncthreads();
    bf16x8 af[4], wf[4];
#pragma unroll
    for (int mt = 0; mt < 4; ++mt)
      af[mt] = *(const bf16x8*)(As + (wr * 64 + mt * 16 + llo) * 32 + lhi * 8);
#pragma unroll
    for (int nt = 0; nt < 4; ++nt)
      wf[nt] = *(const bf16x8*)(Ws + (wc * 64 + nt * 16 + llo) * 32 + lhi * 8);
#pragma unroll
    for (int mt = 0; mt < 4; ++mt)
#pragma unroll
      for (int nt = 0; nt < 4; ++nt)
        acc[mt][nt] = __builtin_amdgcn_mfma_f32_16x16x32_bf16(af[mt], wf[nt], acc[mt][nt], 0, 0, 0);
  }

#pragma unroll
  for (int mt = 0; mt < 4; ++mt)
#pragma unroll
    for (int nt = 0; nt < 4; ++nt)
#pragma unroll
      for (int r = 0; r < 4; ++r) {
        const int row = m0 + wr * 64 + mt * 16 + 4 * lhi + r;
        const int col = n0 + wc * 64 + nt * 16 + llo;
        if (OUTF32)
          ((float*)outp)[(size_t)row * N + col] = acc[mt][nt][r] + bias[col];
        else
          ((u16*)outp)[(size_t)row * N + col] = f2bf(acc[mt][nt][r]);
      }
}

// ---------------------------------------------------------------------------
// MFMA flash attention. 256 thr / 4 waves; wave owns 16 q-rows; KVBLK=64.
// Swapped QK^T: S^T = mfma(A=K, B=Q) -> lane holds one q-column.
// P via per-wave swizzled LDS tile; V staged transposed (Vt[d][kr], swizzled).
// Scale 1/8 pre-folded into Qb. Head h uses KV group h%G.
// ---------------------------------------------------------------------------
__global__ __launch_bounds__(256)
void attn_kernel(const u16* __restrict__ Qb, const u16* __restrict__ KVb,
                 u16* __restrict__ Yb) {
  const int qt = blockIdx.x;          // 32 q-tiles of 64 rows
  const int bh = blockIdx.y;
  const int b = bh >> 4, h = bh & 15, g = h & (G_ - 1);
  const int tid = threadIdx.x;
  const int l = tid & 63, w = tid >> 6;
  const int lhi = l >> 4, llo = l & 15, l7 = l & 7;

  __shared__ __align__(16) u16 Ks[64 * 64];      // [kr][d], 16B-chunk ^ (kr&7)
  __shared__ __align__(16) u16 Vt[64 * 64];      // [d][kr], 16B-chunk ^ (d&7)
  __shared__ __align__(16) u16 Ps[4][16 * 64];   // per-wave [q][kr], ^ (q&7)

  const int q0 = qt * 64;
  const int qrow = q0 + 16 * w + llo;
  const u16* qptr = Qb + (size_t)(b * T_ + qrow) * C_ + h * D_ + 8 * lhi;
  const bf16x8 qf0 = *(const bf16x8*)(qptr);        // d = 8*lhi + j
  const bf16x8 qf1 = *(const bf16x8*)(qptr + 32);   // d = 32 + 8*lhi + j

  const f32x4 zero4 = {0.f, 0.f, 0.f, 0.f};
  f32x4 o[4];
#pragma unroll
  for (int i = 0; i < 4; ++i) o[i] = zero4;
  float m_s = -__builtin_inff();
  float l_s = 0.f;

  // V staging geometry: thread -> (kr pair, d chunk of 8)
  const int vkr = 2 * (tid >> 3);
  const int vdc = tid & 7;
  // K staging geometry: wave w stages rows 16w..16w+15 (2 gload_lds)
  const int kr0s = 16 * w + (l >> 3);
  const int kcs = (l & 7);
  u16* ksl = Ks + 1024 * w;           // wave-uniform
  u16* Pw = Ps[w];
  const int rbase = 4 * lhi;

  for (int kt = 0; kt <= qt; ++kt) {
    const int kv0 = b * T_ + kt * 64;
    // V tile -> regs (issue early, overlaps staging latency)
    const u16* vsrc = KVb + (size_t)(kv0 + vkr) * KVC_ + G_ * D_ + g * D_ + 8 * vdc;
    const uint4 v0 = *(const uint4*)vsrc;
    const uint4 v1 = *(const uint4*)(vsrc + KVC_);

    __syncthreads();   // previous tile's LDS reads complete
    // K -> LDS via global_load_lds, pre-swizzled source (chunk ^= row&7)
    {
      const u16* ks0 = KVb + (size_t)(kv0 + kr0s) * KVC_ + g * D_ + 8 * (kcs ^ (kr0s & 7));
      gload16(ks0, ksl);
      gload16(ks0 + 8 * KVC_, ksl + 512);   // rows +8: same swizzle key
    }
    // V transpose into Vt (pairs of kr -> b32 writes)
    {
      const u16* pv0 = (const u16*)&v0;
      const u16* pv1 = (const u16*)&v1;
#pragma unroll
      for (int i = 0; i < 8; ++i) {
        const int d = 8 * vdc + i;
        const uint32_t val = (uint32_t)pv0[i] | ((uint32_t)pv1[i] << 16);
        const int byte = d * 128 + (((vkr >> 3) ^ (d & 7)) << 4) + (vkr & 7) * 2;
        *(uint32_t*)((char*)Vt + byte) = val;
      }
    }
    __syncthreads();   // staging visible

    // ---- S^T = K @ Q^T : 4 mtiles (kr) x 2 ksteps (d) ----
    f32x4 st[4];
#pragma unroll
    for (int mt = 0; mt < 4; ++mt) st[mt] = zero4;
#pragma unroll
    for (int mt = 0; mt < 4; ++mt) {
      const int krow = 16 * mt + llo;
      const bf16x8 kf0 = *(const bf16x8*)(Ks + krow * 64 + (((lhi + 0) ^ l7) << 3));
      const bf16x8 kf1 = *(const bf16x8*)(Ks + krow * 64 + (((lhi + 4) ^ l7) << 3));
      st[mt] = __builtin_amdgcn_mfma_f32_16x16x32_bf16(kf0, qf0, st[mt], 0, 0, 0);
      st[mt] = __builtin_amdgcn_mfma_f32_16x16x32_bf16(kf1, qf1, st[mt], 0, 0, 0);
    }
    // causal mask (diagonal tile only)
    if (kt == qt) {
#pragma unroll
      for (int mt = 0; mt < 4; ++mt)
#pragma unroll
        for (int r = 0; r < 4; ++r) {
          const int kr_g = kt * 64 + 16 * mt + rbase + r;
          if (kr_g > qrow) st[mt][r] = -__builtin_inff();
        }
    }
    // ---- online softmax (lane owns q = llo; replicas at l^16,l^32) ----
    float mloc = -__builtin_inff();
#pragma unroll
    for (int mt = 0; mt < 4; ++mt)
#pragma unroll
      for (int r = 0; r < 4; ++r) mloc = fmaxf(mloc, st[mt][r]);
    mloc = fmaxf(mloc, __shfl_xor(mloc, 16));
    mloc = fmaxf(mloc, __shfl_xor(mloc, 32));
    const float mnew = fmaxf(m_s, mloc);
    const float corr = __expf(m_s - mnew);   // first tile: exp(-inf)=0
    float p[4][4];
    float ls = 0.f;
#pragma unroll
    for (int mt = 0; mt < 4; ++mt)
#pragma unroll
      for (int r = 0; r < 4; ++r) {
        const float e = __expf(st[mt][r] - mnew);
        p[mt][r] = e;
        ls += e;
      }
    ls += __shfl_xor(ls, 16);
    ls += __shfl_xor(ls, 32);
    l_s = l_s * corr + ls;
    m_s = mnew;
    // rescale O: rows of O are q = rbase+r -> fetch corr from lane rbase+r
    float c4[4];
#pragma unroll
    for (int r = 0; r < 4; ++r) c4[r] = __shfl(corr, rbase + r);
#pragma unroll
    for (int nt = 0; nt < 4; ++nt)
#pragma unroll
      for (int r = 0; r < 4; ++r) o[nt][r] *= c4[r];

    // ---- P -> LDS (bf16, swizzled), then PV ----
#pragma unroll
    for (int mt = 0; mt < 4; ++mt)
#pragma unroll
      for (int pr = 0; pr < 2; ++pr) {
        const int kr0 = 16 * mt + rbase + 2 * pr;
        const uint32_t val =
            (uint32_t)f2bf(p[mt][2 * pr]) | ((uint32_t)f2bf(p[mt][2 * pr + 1]) << 16);
        const int byte = llo * 128 + (((kr0 >> 3) ^ l7) << 4) + (kr0 & 7) * 2;
        *(uint32_t*)((char*)Pw + byte) = val;
      }
#pragma unroll
    for (int ks = 0; ks < 2; ++ks) {
      const bf16x8 pf = *(const bf16x8*)(Pw + llo * 64 + (((lhi + 4 * ks) ^ l7) << 3));
#pragma unroll
      for (int nt = 0; nt < 4; ++nt) {
        const int d_l = 16 * nt + llo;
        const bf16x8 vf = *(const bf16x8*)(Vt + d_l * 64 + (((lhi + 4 * ks) ^ l7) << 3));
        o[nt] = __builtin_amdgcn_mfma_f32_16x16x32_bf16(pf, vf, o[nt], 0, 0, 0);
      }
    }
  }

  // ---- epilogue: divide by l (per O-row), store bf16 ----
  const float invl = 1.f / l_s;
  float i4[4];
#pragma unroll
  for (int r = 0; r < 4; ++r) i4[r] = __shfl(invl, rbase + r);
#pragma unroll
  for (int nt = 0; nt < 4; ++nt)
#pragma unroll
    for (int r = 0; r < 4; ++r) {
      const int qg = q0 + 16 * w + rbase + r;
      const int d = 16 * nt + llo;
      Yb[(size_t)(b * T_ + qg) * C_ + h * D_ + d] = f2bf(o[nt][r] * i4[r]);
    }
}

// ---------------------------------------------------------------------------
extern "C" void kernel_launch(void* const* d_in, const int* in_sizes, int n_in,
                              void* d_out, int out_size, void* d_ws, size_t ws_size,
                              hipStream_t stream) {
  (void)in_sizes; (void)n_in; (void)out_size; (void)ws_size;
  const float* x     = (const float*)d_in[0];
  const float* Wq    = (const float*)d_in[1];
  const float* Wkv   = (const float*)d_in[2];
  const float* Wproj = (const float*)d_in[3];
  const float* bproj = (const float*)d_in[4];
  float* out = (float*)d_out;

  const size_t M = (size_t)B_ * T_;   // 8192
  // Workspace (42 MB): xb 16MB | Qb 16MB | KVb 8MB | wbuf 2MB (time-shared)
  u16* xb   = (u16*)d_ws;             // M*1024 bf16; later aliased as Yb
  u16* Qb   = xb + M * C_;
  u16* KVb  = Qb + M * C_;
  u16* wbuf = KVb + M * KVC_;         // C*C bf16 max, reused for all 3 weights
  u16* Yb   = xb;                     // x consumed after projections

  dim3 blk(256);
  cvt_bf16<<<2048, blk, 0, stream>>>(x, xb, (int)(M * C_ / 4), 1.f);
  // Wq (scale 1/8 folded -> scores pre-scaled) -> Q projection
  cvt_bf16<<<512, blk, 0, stream>>>(Wq, wbuf, C_ * C_ / 4, 0.125f);
  gemm_bf16<0><<<dim3(64, 8), blk, 0, stream>>>(xb, wbuf, nullptr, Qb, C_, C_);
  // Wkv -> KV projection
  cvt_bf16<<<256, blk, 0, stream>>>(Wkv, wbuf, KVC_ * C_ / 4, 1.f);
  gemm_bf16<0><<<dim3(64, 4), blk, 0, stream>>>(xb, wbuf, nullptr, KVb, KVC_, C_);
  // attention (writes Yb = xb; x fully consumed above)
  attn_kernel<<<dim3(32, 64), blk, 0, stream>>>(Qb, KVb, Yb);
  // Wproj -> output projection + bias (f32 out)
  cvt_bf16<<<512, blk, 0, stream>>>(Wproj, wbuf, C_ * C_ / 4, 1.f);
  gemm_bf16<1><<<dim3(64, 8), blk, 0, stream>>>(Yb, wbuf, bproj, out, C_, C_);
}

// Round 8
// 307.160 us; speedup vs baseline: 1.2056x; 1.2056x over previous
//
#include <hip/hip_runtime.h>
#include <math.h>
#include <stdint.h>

#define B_ 4
#define T_ 2048
#define C_ 1024
#define H_ 16
#define G_ 4
#define D_ 64
#define KVC_ 512    // 2*G*D
#define QKV_ 1536   // C + 2*G*D  (packed QKV row stride)
#define KOFF_ 1024  // K block col offset in packed row
#define VOFF_ 1280  // V block col offset in packed row

typedef unsigned short u16;
typedef short bf16x8 __attribute__((ext_vector_type(8)));
typedef float f32x4 __attribute__((ext_vector_type(4)));

__device__ __forceinline__ u16 f2bf(float f) {
  uint32_t u = __builtin_bit_cast(uint32_t, f);
  u += 0x7fffu + ((u >> 16) & 1u);   // RNE
  return (u16)(u >> 16);
}

__device__ __forceinline__ void gload16(const void* g, void* l) {
  __builtin_amdgcn_global_load_lds((const __attribute__((address_space(1))) void*)g,
                                   (__attribute__((address_space(3))) void*)l, 16, 0, 0);
}

// ---------------------------------------------------------------------------
// fp32 -> bf16 (scale folded in), vectorized x4
// ---------------------------------------------------------------------------
__global__ __launch_bounds__(256)
void cvt_bf16(const float* __restrict__ s, u16* __restrict__ d, int n4, float scale) {
  int i = blockIdx.x * 256 + threadIdx.x;
  const int stride = gridDim.x * 256;
  for (; i < n4; i += stride) {
    const float4 v = ((const float4*)s)[i];
    uint2 o;
    o.x = (uint32_t)f2bf(v.x * scale) | ((uint32_t)f2bf(v.y * scale) << 16);
    o.y = (uint32_t)f2bf(v.z * scale) | ((uint32_t)f2bf(v.w * scale) << 16);
    ((uint2*)d)[i] = o;
  }
}

// ---------------------------------------------------------------------------
// bf16 GEMM, m97 structure: out[M,N] = A[M,K] @ W[N,K]^T
// 128x128 tile, BK=32, 256 thr / 4 waves (2x2), 4x4 16x16x32 frags per wave.
// ---------------------------------------------------------------------------
template <int OUTF32>
__global__ __launch_bounds__(256)
void gemm_bf16(const u16* __restrict__ A, const u16* __restrict__ W,
               const float* __restrict__ bias, void* __restrict__ outp,
               int N, int K) {
  __shared__ __align__(16) u16 As[128 * 32];
  __shared__ __align__(16) u16 Ws[128 * 32];
  const int tid = threadIdx.x;
  const int l = tid & 63, w = tid >> 6;
  const int lhi = l >> 4, llo = l & 15;
  const int wr = w >> 1, wc = w & 1;
  const int m0 = blockIdx.x * 128, n0 = blockIdx.y * 128;

  const u16* a_src = A + (size_t)(m0 + 32 * w + (l >> 2)) * K + 8 * (l & 3);
  const u16* w_src = W + (size_t)(n0 + 32 * w + (l >> 2)) * K + 8 * (l & 3);
  u16* asl = As + 1024 * w;
  u16* wsl = Ws + 1024 * w;

  const f32x4 zero4 = {0.f, 0.f, 0.f, 0.f};
  f32x4 acc[4][4];
#pragma unroll
  for (int i = 0; i < 4; ++i)
#pragma unroll
    for (int j = 0; j < 4; ++j) acc[i][j] = zero4;

  for (int k0 = 0; k0 < K; k0 += 32) {
    __syncthreads();
    gload16(a_src + k0, asl);
    gload16(a_src + k0 + 16 * K, asl + 512);
    gload16(w_src + k0, wsl);
    gload16(w_src + k0 + 16 * K, wsl + 512);
    __syncthreads();
    bf16x8 af[4], wf[4];
#pragma unroll
    for (int mt = 0; mt < 4; ++mt)
      af[mt] = *(const bf16x8*)(As + (wr * 64 + mt * 16 + llo) * 32 + lhi * 8);
#pragma unroll
    for (int nt = 0; nt < 4; ++nt)
      wf[nt] = *(const bf16x8*)(Ws + (wc * 64 + nt * 16 + llo) * 32 + lhi * 8);
#pragma unroll
    for (int mt = 0; mt < 4; ++mt)
#pragma unroll
      for (int nt = 0; nt < 4; ++nt)
        acc[mt][nt] = __builtin_amdgcn_mfma_f32_16x16x32_bf16(af[mt], wf[nt], acc[mt][nt], 0, 0, 0);
  }

#pragma unroll
  for (int mt = 0; mt < 4; ++mt)
#pragma unroll
    for (int nt = 0; nt < 4; ++nt)
#pragma unroll
      for (int r = 0; r < 4; ++r) {
        const int row = m0 + wr * 64 + mt * 16 + 4 * lhi + r;
        const int col = n0 + wc * 64 + nt * 16 + llo;
        if (OUTF32)
          ((float*)outp)[(size_t)row * N + col] = acc[mt][nt][r] + bias[col];
        else
          ((u16*)outp)[(size_t)row * N + col] = f2bf(acc[mt][nt][r]);
      }
}

// ---------------------------------------------------------------------------
// MFMA flash attention v2 on packed QKV [M,1536]. 512 thr / 8 waves; QBLK=128;
// KVBLK=64, double-buffered K/V, ONE barrier per tile. Longest-first blocks.
// Swapped QK^T; Vt swizzle ^ (d&7) ^ ((d>>3)&7) both sides -> 2-way max.
// ---------------------------------------------------------------------------
__global__ __launch_bounds__(512)
void attn_kernel(const u16* __restrict__ QKVb, u16* __restrict__ Yb) {
  const int qtb = 15 - blockIdx.x;    // longest-first
  const int bh = blockIdx.y;
  const int b = bh >> 4, h = bh & 15, g = h & (G_ - 1);
  const int tid = threadIdx.x;
  const int l = tid & 63, w = tid >> 6;          // 8 waves
  const int lhi = l >> 4, llo = l & 15, l7 = l & 7;

  __shared__ __align__(16) u16 Ks[2][64 * 64];   // [kr][d], chunk ^ (kr&7)
  __shared__ __align__(16) u16 Vt[2][64 * 64];   // [d][kr], chunk ^ (d&7) ^ ((d>>3)&7)
  __shared__ __align__(16) u16 Ps[8][16 * 64];   // per-wave [q][kr], chunk ^ (q&7)

  const int q0 = qtb * 128;
  const int qrow = q0 + 16 * w + llo;            // this lane's q (as S^T col)
  const u16* qptr = QKVb + (size_t)(b * T_ + qrow) * QKV_ + h * D_ + 8 * lhi;
  const bf16x8 qf0 = *(const bf16x8*)(qptr);
  const bf16x8 qf1 = *(const bf16x8*)(qptr + 32);

  const f32x4 zero4 = {0.f, 0.f, 0.f, 0.f};
  f32x4 o[4];
#pragma unroll
  for (int i = 0; i < 4; ++i) o[i] = zero4;
  float m_s = -__builtin_inff();
  float l_s = 0.f;

  // staging geometry
  const int skr = tid >> 3;                      // K: row 0..63
  const int ksrc_off = 8 * ((tid & 7) ^ (skr & 7));   // pre-swizzled source chunk
  const int vkr = 2 * (tid >> 4);                // V: row pair 0..62
  const int vd4 = 4 * (tid & 15);                // V: 4-d chunk
  u16* Pw = Ps[w];
  const int rbase = 4 * lhi;
  const int qmax_w = q0 + 16 * w + 15;           // wave's max q row
  const int ntiles = 2 * qtb + 2;

  // ---- prologue: stage tile 0 into buffer 0 ----
  {
    const int kv0 = b * T_;
    gload16(QKVb + (size_t)(kv0 + skr) * QKV_ + KOFF_ + g * D_ + ksrc_off,
            Ks[0] + 512 * w);
    const u16* vsrc = QKVb + (size_t)(kv0 + vkr) * QKV_ + VOFF_ + g * D_ + vd4;
    const uint2 a = *(const uint2*)vsrc;
    const uint2 c = *(const uint2*)(vsrc + QKV_);
    const u16* p0 = (const u16*)&a;
    const u16* p1 = (const u16*)&c;
#pragma unroll
    for (int i = 0; i < 4; ++i) {
      const int d = vd4 + i;
      const uint32_t val = (uint32_t)p0[i] | ((uint32_t)p1[i] << 16);
      const int p = (vkr >> 3) ^ (d & 7) ^ ((d >> 3) & 7);
      *(uint32_t*)((char*)Vt[0] + d * 128 + (p << 4) + (vkr & 7) * 2) = val;
    }
  }
  __syncthreads();

  int cur = 0;
  for (int kt = 0; kt < ntiles; ++kt) {
    const bool have_next = (kt + 1) < ntiles;
    uint2 vr0, vr1;
    // ---- issue next tile's loads (K direct to LDS, V to regs) ----
    if (have_next) {
      const int kv0n = b * T_ + (kt + 1) * 64;
      gload16(QKVb + (size_t)(kv0n + skr) * QKV_ + KOFF_ + g * D_ + ksrc_off,
              Ks[cur ^ 1] + 512 * w);
      const u16* vsrc = QKVb + (size_t)(kv0n + vkr) * QKV_ + VOFF_ + g * D_ + vd4;
      vr0 = *(const uint2*)vsrc;
      vr1 = *(const uint2*)(vsrc + QKV_);
    }

    // ---- compute on current buffers (skip fully-masked tiles for this wave) --
    if (kt * 64 <= qmax_w) {
      f32x4 st[4];
#pragma unroll
      for (int mt = 0; mt < 4; ++mt) st[mt] = zero4;
#pragma unroll
      for (int mt = 0; mt < 4; ++mt) {
        const int krow = 16 * mt + llo;
        const u16* kb = Ks[cur] + krow * 64;
        const bf16x8 kf0 = *(const bf16x8*)(kb + ((lhi ^ l7) << 3));
        const bf16x8 kf1 = *(const bf16x8*)(kb + (((lhi + 4) ^ l7) << 3));
        st[mt] = __builtin_amdgcn_mfma_f32_16x16x32_bf16(kf0, qf0, st[mt], 0, 0, 0);
        st[mt] = __builtin_amdgcn_mfma_f32_16x16x32_bf16(kf1, qf1, st[mt], 0, 0, 0);
      }
      // causal mask (only tiles that touch the diagonal for this wave)
      if (kt * 64 + 63 > q0 + 16 * w) {
#pragma unroll
        for (int mt = 0; mt < 4; ++mt)
#pragma unroll
          for (int r = 0; r < 4; ++r) {
            const int kr_g = kt * 64 + 16 * mt + rbase + r;
            if (kr_g > qrow) st[mt][r] = -__builtin_inff();
          }
      }
      // online softmax (lane owns q=llo; replicas across lhi)
      float mloc = -__builtin_inff();
#pragma unroll
      for (int mt = 0; mt < 4; ++mt)
#pragma unroll
        for (int r = 0; r < 4; ++r) mloc = fmaxf(mloc, st[mt][r]);
      mloc = fmaxf(mloc, __shfl_xor(mloc, 16));
      mloc = fmaxf(mloc, __shfl_xor(mloc, 32));
      const float mnew = fmaxf(m_s, mloc);
      const float corr = __expf(m_s - mnew);
      float ls = 0.f;
#pragma unroll
      for (int mt = 0; mt < 4; ++mt)
#pragma unroll
        for (int r = 0; r < 4; ++r) {
          const float e = __expf(st[mt][r] - mnew);
          st[mt][r] = e;
          ls += e;
        }
      ls += __shfl_xor(ls, 16);
      ls += __shfl_xor(ls, 32);
      l_s = l_s * corr + ls;
      m_s = mnew;
      float c4[4];
#pragma unroll
      for (int r = 0; r < 4; ++r) c4[r] = __shfl(corr, rbase + r);
#pragma unroll
      for (int nt = 0; nt < 4; ++nt)
#pragma unroll
        for (int r = 0; r < 4; ++r) o[nt][r] *= c4[r];

      // P -> per-wave LDS (bf16, swizzled)
#pragma unroll
      for (int mt = 0; mt < 4; ++mt)
#pragma unroll
        for (int pr = 0; pr < 2; ++pr) {
          const int kr0 = 16 * mt + rbase + 2 * pr;
          const uint32_t val = (uint32_t)f2bf(st[mt][2 * pr]) |
                               ((uint32_t)f2bf(st[mt][2 * pr + 1]) << 16);
          *(uint32_t*)((char*)Pw + llo * 128 + (((kr0 >> 3) ^ l7) << 4) +
                       (kr0 & 7) * 2) = val;
        }
      // PV
#pragma unroll
      for (int ks = 0; ks < 2; ++ks) {
        const bf16x8 pf = *(const bf16x8*)(Pw + llo * 64 + (((lhi + 4 * ks) ^ l7) << 3));
#pragma unroll
        for (int nt = 0; nt < 4; ++nt) {
          const int d_l = 16 * nt + llo;
          const int fd = l7 ^ ((2 * nt + (llo >> 3)) & 7);
          const bf16x8 vf = *(const bf16x8*)(Vt[cur] + d_l * 64 +
                                             (((lhi + 4 * ks) ^ fd) << 3));
          o[nt] = __builtin_amdgcn_mfma_f32_16x16x32_bf16(pf, vf, o[nt], 0, 0, 0);
        }
      }
    }

    // ---- write next V tile (regs -> LDS, after compute: T14 write-late) ----
    if (have_next) {
      const u16* p0 = (const u16*)&vr0;
      const u16* p1 = (const u16*)&vr1;
#pragma unroll
      for (int i = 0; i < 4; ++i) {
        const int d = vd4 + i;
        const uint32_t val = (uint32_t)p0[i] | ((uint32_t)p1[i] << 16);
        const int p = (vkr >> 3) ^ (d & 7) ^ ((d >> 3) & 7);
        *(uint32_t*)((char*)Vt[cur ^ 1] + d * 128 + (p << 4) + (vkr & 7) * 2) = val;
      }
    }
    __syncthreads();   // drains gload_lds (vmcnt) + orders Vt writes
    cur ^= 1;
  }

  // ---- epilogue (Y layout stays [M,1024]) ----
  const float invl = 1.f / l_s;
  float i4[4];
#pragma unroll
  for (int r = 0; r < 4; ++r) i4[r] = __shfl(invl, rbase + r);
#pragma unroll
  for (int nt = 0; nt < 4; ++nt)
#pragma unroll
    for (int r = 0; r < 4; ++r) {
      const int qg = q0 + 16 * w + rbase + r;
      const int d = 16 * nt + llo;
      Yb[(size_t)(b * T_ + qg) * C_ + h * D_ + d] = f2bf(o[nt][r] * i4[r]);
    }
}

// ---------------------------------------------------------------------------
extern "C" void kernel_launch(void* const* d_in, const int* in_sizes, int n_in,
                              void* d_out, int out_size, void* d_ws, size_t ws_size,
                              hipStream_t stream) {
  (void)in_sizes; (void)n_in; (void)out_size; (void)ws_size;
  const float* x     = (const float*)d_in[0];
  const float* Wq    = (const float*)d_in[1];
  const float* Wkv   = (const float*)d_in[2];
  const float* Wproj = (const float*)d_in[3];
  const float* bproj = (const float*)d_in[4];
  float* out = (float*)d_out;

  const size_t M = (size_t)B_ * T_;   // 8192
  // d_ws (42 MB): xb 16MB | QKVb 24MB | wpb 2MB.  Fused-weight buf lives in
  // d_out scratch (3MB of 32MB; consumed by QKV GEMM before out is written).
  u16* xb    = (u16*)d_ws;            // [M,1024] bf16; later aliased as Yb
  u16* QKVb  = xb + M * C_;           // [M,1536] bf16 packed Q|K|V
  u16* wpb   = QKVb + M * QKV_;       // [1024,1024] bf16
  u16* wqkv  = (u16*)d_out;           // [1536,1024] bf16 scratch in out buffer
  u16* Yb    = xb;

  dim3 blk(256);
  cvt_bf16<<<2048, blk, 0, stream>>>(x, xb, (int)(M * C_ / 4), 1.f);
  // fused weights: rows 0..1023 = Wq * 1/8 (score pre-scale), 1024..1535 = Wkv
  cvt_bf16<<<512, blk, 0, stream>>>(Wq, wqkv, C_ * C_ / 4, 0.125f);
  cvt_bf16<<<256, blk, 0, stream>>>(Wkv, wqkv + (size_t)C_ * C_, KVC_ * C_ / 4, 1.f);
  // fused QKV projection: [M,1024] @ [1536,1024]^T -> [M,1536]
  gemm_bf16<0><<<dim3(64, 12), blk, 0, stream>>>(xb, wqkv, nullptr, QKVb, QKV_, C_);
  // attention (writes Yb = xb; xb consumed by QKV GEMM above)
  attn_kernel<<<dim3(16, 64), dim3(512), 0, stream>>>(QKVb, Yb);
  // output projection + bias (f32 out; overwrites wqkv scratch region)
  cvt_bf16<<<512, blk, 0, stream>>>(Wproj, wpb, C_ * C_ / 4, 1.f);
  gemm_bf16<1><<<dim3(64, 8), blk, 0, stream>>>(Yb, wpb, bproj, out, C_, C_);
}